// Round 5
// baseline (355.801 us; speedup 1.0000x reference)
//
#include <hip/hip_runtime.h>

typedef float fx4 __attribute__((ext_vector_type(4)));
typedef __bf16 bf16x8 __attribute__((ext_vector_type(8)));
typedef unsigned short ushort8 __attribute__((ext_vector_type(8)));
typedef unsigned int uint2v __attribute__((ext_vector_type(2)));
typedef unsigned int uint4v __attribute__((ext_vector_type(4)));

#define MFMA16(a, b, c) __builtin_amdgcn_mfma_f32_16x16x32_bf16((a), (b), (c), 0, 0, 0)

#if __has_builtin(__builtin_amdgcn_exp2f)
#define EXP2(x) __builtin_amdgcn_exp2f(x)
#else
#define EXP2(x) exp2f(x)
#endif

__device__ __forceinline__ unsigned short f2bf(float f) {
  return __builtin_bit_cast(unsigned short, (__bf16)f);
}

__device__ __forceinline__ ushort8 pack8(fx4 a, fx4 b) {
  ushort8 v;
  v[0] = f2bf(a[0]); v[1] = f2bf(a[1]); v[2] = f2bf(a[2]); v[3] = f2bf(a[3]);
  v[4] = f2bf(b[0]); v[5] = f2bf(b[1]); v[6] = f2bf(b[2]); v[7] = f2bf(b[3]);
  return v;
}

__device__ __forceinline__ uint2v pack2(fx4 v) {
  uint2v r;
  r[0] = (unsigned int)f2bf(v[0]) | ((unsigned int)f2bf(v[1]) << 16);
  r[1] = (unsigned int)f2bf(v[2]) | ((unsigned int)f2bf(v[3]) << 16);
  return r;
}

// C-layout (col=x on l16, row=y on quad*4+r, two 16-row source tiles A,B) ->
// B/A-fragment (lane l16 = x, k-dim = y). Round-2 verified quad-redistribute
// (the permlane variant measured slower at this shape; reverted).
__device__ __forceinline__ bf16x8 xfrm(uint2v A, uint2v B, int quad, int src0, int src1) {
  uint4v pf;
#pragma unroll
  for (int d = 0; d < 2; d++) {
    int a0 = __shfl((int)A[d], src0, 64);
    int b0 = __shfl((int)B[d], src0, 64);
    pf[d] = (unsigned int)((quad < 2) ? a0 : b0);
    int a1 = __shfl((int)A[d], src1, 64);
    int b1 = __shfl((int)B[d], src1, 64);
    pf[2 + d] = (unsigned int)((quad < 2) ? a1 : b1);
  }
  return __builtin_bit_cast(bf16x8, pf);
}

// async global->LDS, 16B per lane; LDS dest is wave-uniform base, lane i lands at +16*i
__device__ __forceinline__ void gl2lds16(const unsigned short* g, void* lds_base) {
  __builtin_amdgcn_global_load_lds(
      (const __attribute__((address_space(1))) void*)(unsigned long long)(g),
      (__attribute__((address_space(3))) void*)(unsigned int)(unsigned long long)(lds_base),
      16, 0, 0);
}

// ---------- merged prep: PE table | img/W cvt | Wqkv cvt | class-token row + stats init ----------
// block ranges: [0,591) pe | [591,10287) cvt | [10287,10359) wcvt | [10359,10487) cls.
// cls initializes sums/sqs by DIRECT STORE (k_tokens atomicAdds on top, next kernel).
__global__ __launch_bounds__(256) void k_prep(
    const float* __restrict__ img, const float* __restrict__ W,
    const float* __restrict__ Wq, const float* __restrict__ Wk, const float* __restrict__ Wv,
    const float* __restrict__ ct,
    float* __restrict__ pe, unsigned short* __restrict__ imgbf, unsigned short* __restrict__ wbf,
    unsigned short* __restrict__ wqkv,
    float* __restrict__ out, float* __restrict__ sums, float* __restrict__ sqs) {
  const int bid = blockIdx.x, tid = threadIdx.x;
  if (bid < 591) {
    int idx = bid * 256 + tid;  // < 151296 exact
    int s = idx / 768;
    int j = idx - s * 768;
    int jj = j & ~1;
    float ang = (float)s * expf((float)jj * (-9.210340371976184f / 768.0f));
    pe[idx] = (j & 1) ? cosf(ang) : sinf(ang);
  } else if (bid < 10287) {
    size_t i = ((size_t)(bid - 591) * 256 + tid) * 8;  // < 19857408 exact
    const float* src;
    unsigned short* dst;
    if (i < 19267584) { src = img + i; dst = imgbf + i; }
    else { size_t j = i - 19267584; src = W + j; dst = wbf + j; }
    const fx4* p = (const fx4*)src;
    *(ushort8*)dst = pack8(p[0], p[1]);
  } else if (bid < 10359) {
    int i = ((bid - 10287) * 256 + tid) * 8;  // < 147456 exact
    const float* src = (i < 49152) ? (Wq + i) : (i < 98304 ? Wk + (i - 49152) : Wv + (i - 98304));
    const fx4* p = (const fx4*)src;
    *(ushort8*)(wqkv + i) = pack8(p[0], p[1]);
  } else {
    // class token row (s=0): PE row 0 is closed-form (j even -> 0, j odd -> 1)
    const int b = bid - 10359;
    float s = 0.f, q = 0.f;
#pragma unroll
    for (int it = 0; it < 3; it++) {
      int j = tid + it * 256;
      float v = ct[j] + ((j & 1) ? 1.f : 0.f);
      out[(size_t)b * 197 * 768 + j] = v;
      s += v; q += v * v;
    }
    for (int off = 32; off > 0; off >>= 1) { s += __shfl_down(s, off); q += __shfl_down(q, off); }
    __shared__ float rs[4], rq[4];
    int w = tid >> 6;
    if ((tid & 63) == 0) { rs[w] = s; rq[w] = q; }
    __syncthreads();
    if (tid == 0) {
      sums[b] = rs[0] + rs[1] + rs[2] + rs[3];  // initializer store, not atomic
      sqs[b] = rq[0] + rq[1] + rq[2] + rq[3];
    }
  }
}

// ---------- tokens = patches @ W_map^T + b_map + PE; also LN partial stats ----------
// 1D grid 1176 = 8*147 (bijective XCD chunking): the 6 n-tiles of each m-tile run
// consecutively on ONE XCD -> A-panel read once from HBM, B-panels L2-resident.
__global__ __launch_bounds__(256) void k_tokens(
    const unsigned short* __restrict__ imgbf, const unsigned short* __restrict__ wbf,
    const float* __restrict__ bmap, const float* __restrict__ pe,
    float* __restrict__ out, float* __restrict__ sums, float* __restrict__ sqs) {
  __shared__ __align__(16) ushort8 Sf[16 * 64];  // blobs 0-7: A(128x32), 8-15: B(128x32)
  const int tid = threadIdx.x;
  const int idx = (blockIdx.x & 7) * 147 + (blockIdx.x >> 3);
  const int m0 = (idx / 6) * 128;
  const int n0 = (idx % 6) * 128;
  const int lane = tid & 63;
  const int w = tid >> 6;
  const int quad = lane >> 4, l16 = lane & 15;
  const int m_off = (w & 1) * 64, n_off = (w >> 1) * 64;

  fx4 acc[4][4];
#pragma unroll
  for (int i = 0; i < 4; i++)
#pragma unroll
    for (int j = 0; j < 4; j++) acc[i][j] = (fx4){0.f, 0.f, 0.f, 0.f};

  const unsigned short* pA = imgbf + (size_t)(m0 + w * 16 + l16) * 768 + quad * 8;
  const unsigned short* pB = wbf + (size_t)(n0 + w * 16 + l16) * 768 + quad * 8;
  void* lA0 = (void*)&Sf[(w) * 64];
  void* lA1 = (void*)&Sf[(4 + w) * 64];
  void* lB0 = (void*)&Sf[(8 + w) * 64];
  void* lB1 = (void*)&Sf[(12 + w) * 64];

  for (int k0 = 0; k0 < 768; k0 += 32) {
    __syncthreads();
    gl2lds16(pA + k0, lA0);
    gl2lds16(pA + 64 * 768 + k0, lA1);
    gl2lds16(pB + k0, lB0);
    gl2lds16(pB + 64 * 768 + k0, lB1);
    __syncthreads();
    bf16x8 a[4], b[4];
#pragma unroll
    for (int mt = 0; mt < 4; mt++)
      a[mt] = __builtin_bit_cast(bf16x8, Sf[((w & 1) * 4 + mt) * 64 + lane]);
#pragma unroll
    for (int nt = 0; nt < 4; nt++)
      b[nt] = __builtin_bit_cast(bf16x8, Sf[(8 + (w >> 1) * 4 + nt) * 64 + lane]);
#pragma unroll
    for (int mt = 0; mt < 4; mt++)
#pragma unroll
      for (int nt = 0; nt < 4; nt++) acc[mt][nt] = MFMA16(a[mt], b[nt], acc[mt][nt]);
  }

  float s0 = 0.f, q0 = 0.f, s1 = 0.f, q1 = 0.f;
  const int b0 = m0 / 196;
#pragma unroll
  for (int mt = 0; mt < 4; mt++) {
#pragma unroll
    for (int nt = 0; nt < 4; nt++) {
      const int col = n0 + n_off + nt * 16 + l16;
      const float bc = bmap[col];
#pragma unroll
      for (int r = 0; r < 4; r++) {
        const int gm = m0 + m_off + mt * 16 + quad * 4 + r;
        const int bb = gm / 196;
        const int ss = gm - bb * 196 + 1;  // class token occupies s=0
        float val = acc[mt][nt][r] + bc + pe[ss * 768 + col];
        out[((size_t)bb * 197 + ss) * 768 + col] = val;
        if (bb == b0) { s0 += val; q0 += val * val; }
        else          { s1 += val; q1 += val * val; }
      }
    }
  }
  for (int off = 32; off > 0; off >>= 1) {
    s0 += __shfl_down(s0, off); q0 += __shfl_down(q0, off);
    s1 += __shfl_down(s1, off); q1 += __shfl_down(q1, off);
  }
  if (lane == 0) {
    atomicAdd(&sums[b0], s0);
    atomicAdd(&sqs[b0], q0);
    if (b0 + 1 < 128) { atomicAdd(&sums[b0 + 1], s1); atomicAdd(&sqs[b0 + 1], q1); }
  }
}

// ---------- fused LN + QKV projection + attention, per (b,h); round-2 structure ----------
// Wave w owns s-tiles {2w, 2w+1, 2w+8, 2w+9}: X_ln built once feeds Q (regs), K (LDS),
// V (LDS blob jp = w / w+4). Q prescaled by 0.125*log2e (softmax = bare v_exp_f32).
// LN mean/rstd inline from sums/sqs. LDS 53248 B -> 3 blocks/CU. Verified 8-shfl xfrm.
__global__ __launch_bounds__(256, 3) void k_fused(
    const float* tok, const float* __restrict__ sums, const float* __restrict__ sqs,
    const float* __restrict__ lnw, const float* __restrict__ lnb,
    const unsigned short* __restrict__ wqkv,
    const float* __restrict__ bq, const float* __restrict__ bk, const float* __restrict__ bv,
    float* out) {
  __shared__ __align__(16) ushort8 Kf[26 * 64];   // [t-tile][kk][lane] 26624 B
  __shared__ __align__(16) ushort8 Vf[24 * 64];   // [et][jp<6][lane]   24576 B
  __shared__ __align__(16) ushort8 Vt[4 * 32];    // [et][lane<32]       2048 B
  const int tid = threadIdx.x;
  const int bh = blockIdx.x;
  const int b = bh / 12;
  const int h = bh - b * 12;
  const int lane = tid & 63;
  const int w = tid >> 6;
  const int quad = lane >> 4;
  const int l16 = lane & 15;
  const int src0 = l16 + ((quad & 1) << 5);
  const int src1 = src0 + 16;
  const float invN = 1.0f / 151296.0f;
  const float mean = sums[b] * invN;
  const float rstd = rsqrtf(sqs[b] * invN - mean * mean + 1e-5f);
  const int hcol = h * 64;

  bf16x8 qfr[4][2];

  bf16x8 wq[4][2], wk[4][2], wv[4][2];
#pragma unroll
  for (int et = 0; et < 4; et++) {
    const int ro = (et * 16 + l16) * 64 + quad * 8;
#pragma unroll
    for (int kk = 0; kk < 2; kk++) {
      wq[et][kk] = *(const bf16x8*)(wqkv + hcol * 64 + ro + kk * 32);
      wk[et][kk] = *(const bf16x8*)(wqkv + 49152 + hcol * 64 + ro + kk * 32);
      wv[et][kk] = *(const bf16x8*)(wqkv + 98304 + hcol * 64 + ro + kk * 32);
    }
  }

  // ---- staging: wave w does tile-pairs jp = w, w+4 (tiles 2jp, 2jp+1) ----
#pragma unroll
  for (int pi = 0; pi < 2; pi++) {
    const int jp = w + 4 * pi;
    if (jp <= 6) {
      bf16x8 xf[2][2];  // [tile-in-pair][kk]
#pragma unroll
      for (int s2 = 0; s2 < 2; s2++) {
        const int tt = 2 * jp + s2;
        if (tt < 13) {
          int ss = tt * 16 + l16;
          ss = (ss < 197) ? ss : 196;  // clamped rows only feed masked outputs
#pragma unroll
          for (int kk = 0; kk < 2; kk++) {
            const int col = hcol + kk * 32 + quad * 8;
            const fx4* px = (const fx4*)(tok + (size_t)(b * 197 + ss) * 768 + col);
            const fx4* pw = (const fx4*)(lnw + (size_t)ss * 768 + col);
            const fx4* pb = (const fx4*)(lnb + (size_t)ss * 768 + col);
            fx4 y0 = (px[0] - mean) * rstd * pw[0] + pb[0];
            fx4 y1 = (px[1] - mean) * rstd * pw[1] + pb[1];
            xf[s2][kk] = __builtin_bit_cast(bf16x8, pack8(y0, y1));
          }
          fx4 aq[4], ak[4];
#pragma unroll
          for (int et = 0; et < 4; et++) {
            aq[et] = (fx4){0.f, 0.f, 0.f, 0.f};
            ak[et] = (fx4){0.f, 0.f, 0.f, 0.f};
          }
#pragma unroll
          for (int kk = 0; kk < 2; kk++)
#pragma unroll
            for (int et = 0; et < 4; et++) {
              aq[et] = MFMA16(wq[et][kk], xf[s2][kk], aq[et]);  // D[e][s], col=s=l16
              ak[et] = MFMA16(wk[et][kk], xf[s2][kk], ak[et]);
            }
          uint2v qp[4], kp[4];
#pragma unroll
          for (int et = 0; et < 4; et++) {
            fx4 bqv = *(const fx4*)(bq + hcol + et * 16 + quad * 4);
            fx4 bkv = *(const fx4*)(bk + hcol + et * 16 + quad * 4);
            qp[et] = pack2((aq[et] + bqv) * 0.18033688f);  // 0.125 * log2(e)
            kp[et] = pack2(ak[et] + bkv);
          }
          const int qi = pi * 2 + s2;
#pragma unroll
          for (int kk = 0; kk < 2; kk++) {
            qfr[qi][kk] = xfrm(qp[2 * kk], qp[2 * kk + 1], quad, src0, src1);
            bf16x8 kfrag = xfrm(kp[2 * kk], kp[2 * kk + 1], quad, src0, src1);
            Kf[(tt * 2 + kk) * 64 + lane] = __builtin_bit_cast(ushort8, kfrag);
          }
        }
      }
      // V for the pair: D[t][e], col=e=l16 (reuses xf)
      fx4 av[2][4];
#pragma unroll
      for (int s2 = 0; s2 < 2; s2++)
#pragma unroll
        for (int et = 0; et < 4; et++) av[s2][et] = (fx4){0.f, 0.f, 0.f, 0.f};
#pragma unroll
      for (int s2 = 0; s2 < 2; s2++) {
        const int tt = 2 * jp + s2;
        if (tt < 13) {
#pragma unroll
          for (int kk = 0; kk < 2; kk++)
#pragma unroll
            for (int et = 0; et < 4; et++)
              av[s2][et] = MFMA16(xf[s2][kk], wv[et][kk], av[s2][et]);
        }
      }
#pragma unroll
      for (int et = 0; et < 4; et++) {
        const float bvv = bv[hcol + et * 16 + l16];
        fx4 bb4 = (fx4){bvv, bvv, bvv, bvv};
        uint2v v0 = pack2(av[0][et] + bb4);
        uint2v v1 = pack2(av[1][et] + bb4);
        bf16x8 vfrag = xfrm(v0, v1, quad, src0, src1);
        if (jp < 6) Vf[(et * 6 + jp) * 64 + lane] = __builtin_bit_cast(ushort8, vfrag);
        else if (quad < 2) Vt[et * 32 + lane] = __builtin_bit_cast(ushort8, vfrag);
      }
    }
  }
  __syncthreads();

  // ---- attention: wave w handles mt in {2w, 2w+1, 2w+8, 2w+9} ----
#pragma unroll
  for (int qi = 0; qi < 4; qi++) {
    const int mt = 2 * w + (qi >> 1) * 8 + (qi & 1);
    if (mt < 13) {
      fx4 sacc[13];
#pragma unroll
      for (int nt = 0; nt < 13; nt++) sacc[nt] = (fx4){0.f, 0.f, 0.f, 0.f};
#pragma unroll
      for (int kk = 0; kk < 2; kk++) {
        bf16x8 qf = qfr[qi][kk];
#pragma unroll
        for (int nt = 0; nt < 13; nt++) {
          bf16x8 kf = __builtin_bit_cast(bf16x8, Kf[(nt * 2 + kk) * 64 + lane]);
          sacc[nt] = MFMA16(kf, qf, sacc[nt]);  // D[t][m]: col=m=l16, row=t
        }
      }
      // softmax over t; Q prescaled so p = 2^s
      float sm = 0.f;
      uint2v pk[13];
#pragma unroll
      for (int nt = 0; nt < 13; nt++) {
        fx4 p;
#pragma unroll
        for (int r = 0; r < 4; r++) {
          const bool valid = (nt < 12) | (quad * 4 + r < 5);  // t < 197
          p[r] = valid ? EXP2(sacc[nt][r]) : 0.f;
          sm += p[r];
        }
        pk[nt] = pack2(p);
      }
      sm += __shfl_xor(sm, 16);
      sm += __shfl_xor(sm, 32);
      const float inv = 1.0f / sm;

      fx4 oacc[4];
#pragma unroll
      for (int et = 0; et < 4; et++) oacc[et] = (fx4){0.f, 0.f, 0.f, 0.f};
#pragma unroll
      for (int kk = 0; kk < 7; kk++) {
        uint4v pf;
        if (kk < 6) {
          const int nA = 2 * kk, nB = 2 * kk + 1;
#pragma unroll
          for (int d = 0; d < 2; d++) {
            int a0 = __shfl((int)pk[nA][d], src0, 64);
            int b0 = __shfl((int)pk[nB][d], src0, 64);
            pf[d] = (unsigned int)((quad < 2) ? a0 : b0);
            int a1 = __shfl((int)pk[nA][d], src1, 64);
            int b1 = __shfl((int)pk[nB][d], src1, 64);
            pf[2 + d] = (unsigned int)((quad < 2) ? a1 : b1);
          }
        } else {
#pragma unroll
          for (int d = 0; d < 2; d++) {
            int a0 = __shfl((int)pk[12][d], src0, 64);
            pf[d] = (quad < 2) ? (unsigned int)a0 : 0u;
            int a1 = __shfl((int)pk[12][d], src1, 64);
            pf[2 + d] = (quad < 2) ? (unsigned int)a1 : 0u;
          }
        }
        bf16x8 pfrag = __builtin_bit_cast(bf16x8, pf);
#pragma unroll
        for (int et = 0; et < 4; et++) {
          bf16x8 vf;
          if (kk < 6) {
            vf = __builtin_bit_cast(bf16x8, Vf[(et * 6 + kk) * 64 + lane]);
          } else if (quad < 2) {
            vf = __builtin_bit_cast(bf16x8, Vt[et * 32 + lane]);
          } else {
            ushort8 z = {0, 0, 0, 0, 0, 0, 0, 0};
            vf = __builtin_bit_cast(bf16x8, z);
          }
          oacc[et] = MFMA16(vf, pfrag, oacc[et]);  // D[e][m]: col=m=l16, row=e
        }
      }
      const int sg = mt * 16 + l16;
      if (sg < 197) {
        float* op = out + ((size_t)b * 197 + sg) * 768 + hcol + quad * 4;
#pragma unroll
        for (int et = 0; et < 4; et++) {
          fx4 cur = *(const fx4*)(op + et * 16);
          cur += oacc[et] * inv;
          *(fx4*)(op + et * 16) = cur;
        }
      }
    }
  }
}

extern "C" void kernel_launch(void* const* d_in, const int* in_sizes, int n_in,
                              void* d_out, int out_size, void* d_ws, size_t ws_size,
                              hipStream_t stream) {
  (void)in_sizes; (void)n_in; (void)out_size; (void)ws_size;
  const float* img  = (const float*)d_in[0];
  const float* Wmap = (const float*)d_in[1];
  const float* bmap = (const float*)d_in[2];
  const float* ct   = (const float*)d_in[3];
  const float* lnw  = (const float*)d_in[4];
  const float* lnb  = (const float*)d_in[5];
  const float* Wq   = (const float*)d_in[6];
  const float* bq   = (const float*)d_in[7];
  const float* Wk   = (const float*)d_in[8];
  const float* bk   = (const float*)d_in[9];
  const float* Wv   = (const float*)d_in[10];
  const float* bv   = (const float*)d_in[11];
  float* out = (float*)d_out;

  // ws layout (~41 MiB): pe | sums | sqs | W_bf16 | img_bf16 | Wqkv_bf16
  float* pe   = (float*)d_ws;                 // 151296 f
  float* sums = pe + 151296;                  // 128 f
  float* sqs  = sums + 128;                   // 128 f
  unsigned short* wbf   = (unsigned short*)(sqs + 128);  // 589824 u16
  unsigned short* imgbf = wbf + 589824;                  // 19267584 u16
  unsigned short* wqkv  = imgbf + (size_t)19267584;      // 147456 u16

  k_prep<<<10487, 256, 0, stream>>>(img, Wmap, Wq, Wk, Wv, ct,
                                    pe, imgbf, wbf, wqkv, out, sums, sqs);
  k_tokens<<<1176, 256, 0, stream>>>(imgbf, wbf, bmap, pe, out, sums, sqs);
  k_fused<<<1536, 256, 0, stream>>>(out, sums, sqs, lnw, lnb, wqkv, bq, bk, bv, out);
}

// Round 6
// 338.078 us; speedup vs baseline: 1.0524x; 1.0524x over previous
//
#include <hip/hip_runtime.h>

typedef float fx4 __attribute__((ext_vector_type(4)));
typedef __bf16 bf16x8 __attribute__((ext_vector_type(8)));
typedef unsigned short ushort8 __attribute__((ext_vector_type(8)));
typedef unsigned int uint2v __attribute__((ext_vector_type(2)));
typedef unsigned int uint4v __attribute__((ext_vector_type(4)));

#define MFMA16(a, b, c) __builtin_amdgcn_mfma_f32_16x16x32_bf16((a), (b), (c), 0, 0, 0)

#if __has_builtin(__builtin_amdgcn_exp2f)
#define EXP2(x) __builtin_amdgcn_exp2f(x)
#else
#define EXP2(x) exp2f(x)
#endif

__device__ __forceinline__ unsigned short f2bf(float f) {
  return __builtin_bit_cast(unsigned short, (__bf16)f);
}

__device__ __forceinline__ ushort8 pack8(fx4 a, fx4 b) {
  ushort8 v;
  v[0] = f2bf(a[0]); v[1] = f2bf(a[1]); v[2] = f2bf(a[2]); v[3] = f2bf(a[3]);
  v[4] = f2bf(b[0]); v[5] = f2bf(b[1]); v[6] = f2bf(b[2]); v[7] = f2bf(b[3]);
  return v;
}

__device__ __forceinline__ uint2v pack2(fx4 v) {
  uint2v r;
  r[0] = (unsigned int)f2bf(v[0]) | ((unsigned int)f2bf(v[1]) << 16);
  r[1] = (unsigned int)f2bf(v[2]) | ((unsigned int)f2bf(v[3]) << 16);
  return r;
}

// C-layout (col=x on l16, row=y on quad*4+r, two 16-row source tiles A,B) ->
// B/A-fragment (lane l16 = x, k-dim = y). Round-2 verified quad-redistribute
// (permlane variant measured -24us worse at this shape in R4; keep shfl form).
__device__ __forceinline__ bf16x8 xfrm(uint2v A, uint2v B, int quad, int src0, int src1) {
  uint4v pf;
#pragma unroll
  for (int d = 0; d < 2; d++) {
    int a0 = __shfl((int)A[d], src0, 64);
    int b0 = __shfl((int)B[d], src0, 64);
    pf[d] = (unsigned int)((quad < 2) ? a0 : b0);
    int a1 = __shfl((int)A[d], src1, 64);
    int b1 = __shfl((int)B[d], src1, 64);
    pf[2 + d] = (unsigned int)((quad < 2) ? a1 : b1);
  }
  return __builtin_bit_cast(bf16x8, pf);
}

// async global->LDS, 16B per lane; LDS dest is wave-uniform base, lane i lands at +16*i
__device__ __forceinline__ void gl2lds16(const unsigned short* g, void* lds_base) {
  __builtin_amdgcn_global_load_lds(
      (const __attribute__((address_space(1))) void*)(unsigned long long)(g),
      (__attribute__((address_space(3))) void*)(unsigned int)(unsigned long long)(lds_base),
      16, 0, 0);
}

// ---------- merged prep: PE table | img/W cvt | Wqkv cvt | class-token row + stats init ----------
// block ranges: [0,591) pe | [591,10287) cvt | [10287,10359) wcvt | [10359,10487) cls.
// cls initializes sums/sqs by DIRECT STORE (k_tokens atomicAdds on top, next kernel).
__global__ __launch_bounds__(256) void k_prep(
    const float* __restrict__ img, const float* __restrict__ W,
    const float* __restrict__ Wq, const float* __restrict__ Wk, const float* __restrict__ Wv,
    const float* __restrict__ ct,
    float* __restrict__ pe, unsigned short* __restrict__ imgbf, unsigned short* __restrict__ wbf,
    unsigned short* __restrict__ wqkv,
    float* __restrict__ out, float* __restrict__ sums, float* __restrict__ sqs) {
  const int bid = blockIdx.x, tid = threadIdx.x;
  if (bid < 591) {
    int idx = bid * 256 + tid;  // < 151296 exact
    int s = idx / 768;
    int j = idx - s * 768;
    int jj = j & ~1;
    float ang = (float)s * expf((float)jj * (-9.210340371976184f / 768.0f));
    pe[idx] = (j & 1) ? cosf(ang) : sinf(ang);
  } else if (bid < 10287) {
    size_t i = ((size_t)(bid - 591) * 256 + tid) * 8;  // < 19857408 exact
    const float* src;
    unsigned short* dst;
    if (i < 19267584) { src = img + i; dst = imgbf + i; }
    else { size_t j = i - 19267584; src = W + j; dst = wbf + j; }
    const fx4* p = (const fx4*)src;
    *(ushort8*)dst = pack8(p[0], p[1]);
  } else if (bid < 10359) {
    int i = ((bid - 10287) * 256 + tid) * 8;  // < 147456 exact
    const float* src = (i < 49152) ? (Wq + i) : (i < 98304 ? Wk + (i - 49152) : Wv + (i - 98304));
    const fx4* p = (const fx4*)src;
    *(ushort8*)(wqkv + i) = pack8(p[0], p[1]);
  } else {
    // class token row (s=0): PE row 0 is closed-form (j even -> 0, j odd -> 1)
    const int b = bid - 10359;
    float s = 0.f, q = 0.f;
#pragma unroll
    for (int it = 0; it < 3; it++) {
      int j = tid + it * 256;
      float v = ct[j] + ((j & 1) ? 1.f : 0.f);
      out[(size_t)b * 197 * 768 + j] = v;
      s += v; q += v * v;
    }
    for (int off = 32; off > 0; off >>= 1) { s += __shfl_down(s, off); q += __shfl_down(q, off); }
    __shared__ float rs[4], rq[4];
    int w = tid >> 6;
    if ((tid & 63) == 0) { rs[w] = s; rq[w] = q; }
    __syncthreads();
    if (tid == 0) {
      sums[b] = rs[0] + rs[1] + rs[2] + rs[3];  // initializer store, not atomic
      sqs[b] = rq[0] + rq[1] + rq[2] + rq[3];
    }
  }
}

// ---------- tokens = patches @ W_map^T + b_map + PE; also LN partial stats ----------
// 1D grid 1176 = 8*147 (bijective XCD chunking): the 6 n-tiles of each m-tile run
// consecutively on ONE XCD -> A-panel read once from HBM, B-panels L2-resident.
__global__ __launch_bounds__(256) void k_tokens(
    const unsigned short* __restrict__ imgbf, const unsigned short* __restrict__ wbf,
    const float* __restrict__ bmap, const float* __restrict__ pe,
    float* __restrict__ out, float* __restrict__ sums, float* __restrict__ sqs) {
  __shared__ __align__(16) ushort8 Sf[16 * 64];  // blobs 0-7: A(128x32), 8-15: B(128x32)
  const int tid = threadIdx.x;
  const int idx = (blockIdx.x & 7) * 147 + (blockIdx.x >> 3);
  const int m0 = (idx / 6) * 128;
  const int n0 = (idx % 6) * 128;
  const int lane = tid & 63;
  const int w = tid >> 6;
  const int quad = lane >> 4, l16 = lane & 15;
  const int m_off = (w & 1) * 64, n_off = (w >> 1) * 64;

  fx4 acc[4][4];
#pragma unroll
  for (int i = 0; i < 4; i++)
#pragma unroll
    for (int j = 0; j < 4; j++) acc[i][j] = (fx4){0.f, 0.f, 0.f, 0.f};

  const unsigned short* pA = imgbf + (size_t)(m0 + w * 16 + l16) * 768 + quad * 8;
  const unsigned short* pB = wbf + (size_t)(n0 + w * 16 + l16) * 768 + quad * 8;
  void* lA0 = (void*)&Sf[(w) * 64];
  void* lA1 = (void*)&Sf[(4 + w) * 64];
  void* lB0 = (void*)&Sf[(8 + w) * 64];
  void* lB1 = (void*)&Sf[(12 + w) * 64];

  for (int k0 = 0; k0 < 768; k0 += 32) {
    __syncthreads();
    gl2lds16(pA + k0, lA0);
    gl2lds16(pA + 64 * 768 + k0, lA1);
    gl2lds16(pB + k0, lB0);
    gl2lds16(pB + 64 * 768 + k0, lB1);
    __syncthreads();
    bf16x8 a[4], b[4];
#pragma unroll
    for (int mt = 0; mt < 4; mt++)
      a[mt] = __builtin_bit_cast(bf16x8, Sf[((w & 1) * 4 + mt) * 64 + lane]);
#pragma unroll
    for (int nt = 0; nt < 4; nt++)
      b[nt] = __builtin_bit_cast(bf16x8, Sf[(8 + (w >> 1) * 4 + nt) * 64 + lane]);
#pragma unroll
    for (int mt = 0; mt < 4; mt++)
#pragma unroll
      for (int nt = 0; nt < 4; nt++) acc[mt][nt] = MFMA16(a[mt], b[nt], acc[mt][nt]);
  }

  float s0 = 0.f, q0 = 0.f, s1 = 0.f, q1 = 0.f;
  const int b0 = m0 / 196;
#pragma unroll
  for (int mt = 0; mt < 4; mt++) {
#pragma unroll
    for (int nt = 0; nt < 4; nt++) {
      const int col = n0 + n_off + nt * 16 + l16;
      const float bc = bmap[col];
#pragma unroll
      for (int r = 0; r < 4; r++) {
        const int gm = m0 + m_off + mt * 16 + quad * 4 + r;
        const int bb = gm / 196;
        const int ss = gm - bb * 196 + 1;  // class token occupies s=0
        float val = acc[mt][nt][r] + bc + pe[ss * 768 + col];
        out[((size_t)bb * 197 + ss) * 768 + col] = val;
        if (bb == b0) { s0 += val; q0 += val * val; }
        else          { s1 += val; q1 += val * val; }
      }
    }
  }
  for (int off = 32; off > 0; off >>= 1) {
    s0 += __shfl_down(s0, off); q0 += __shfl_down(q0, off);
    s1 += __shfl_down(s1, off); q1 += __shfl_down(q1, off);
  }
  if (lane == 0) {
    atomicAdd(&sums[b0], s0);
    atomicAdd(&sqs[b0], q0);
    if (b0 + 1 < 128) { atomicAdd(&sums[b0 + 1], s1); atomicAdd(&sqs[b0 + 1], q1); }
  }
}

// ---------- fused LN + QKV projection + attention, per (b,h) ----------
// Staging: round-2 structure (verified). Attention: 2-deep q-tile pipeline —
// pairs {2w,2w+1},{2w+8,2w+9} with interleaved QK/softmax/PV phases; each Kf/Vf
// LDS fragment read ONCE feeds both tiles' MFMAs; setprio(1) around MFMA clusters;
// out-RMW reads issued post-softmax to hide under PV. VGPR-heavy -> 2 blocks/CU
// (rounds 1-3 showed occupancy is not the binding constraint; latency chain is).
__global__ __launch_bounds__(256, 2) void k_fused(
    const float* tok, const float* __restrict__ sums, const float* __restrict__ sqs,
    const float* __restrict__ lnw, const float* __restrict__ lnb,
    const unsigned short* __restrict__ wqkv,
    const float* __restrict__ bq, const float* __restrict__ bk, const float* __restrict__ bv,
    float* out) {
  __shared__ __align__(16) ushort8 Kf[26 * 64];   // [t-tile][kk][lane] 26624 B
  __shared__ __align__(16) ushort8 Vf[24 * 64];   // [et][jp<6][lane]   24576 B
  __shared__ __align__(16) ushort8 Vt[4 * 32];    // [et][lane<32]       2048 B
  const int tid = threadIdx.x;
  const int bh = blockIdx.x;
  const int b = bh / 12;
  const int h = bh - b * 12;
  const int lane = tid & 63;
  const int w = tid >> 6;
  const int quad = lane >> 4;
  const int l16 = lane & 15;
  const int src0 = l16 + ((quad & 1) << 5);
  const int src1 = src0 + 16;
  const float invN = 1.0f / 151296.0f;
  const float mean = sums[b] * invN;
  const float rstd = rsqrtf(sqs[b] * invN - mean * mean + 1e-5f);
  const int hcol = h * 64;

  bf16x8 qfr[4][2];
  {
    ushort8 z8 = {0, 0, 0, 0, 0, 0, 0, 0};
#pragma unroll
    for (int qi = 0; qi < 4; qi++)
#pragma unroll
      for (int kk = 0; kk < 2; kk++) qfr[qi][kk] = __builtin_bit_cast(bf16x8, z8);
  }

  bf16x8 wq[4][2], wk[4][2], wv[4][2];
#pragma unroll
  for (int et = 0; et < 4; et++) {
    const int ro = (et * 16 + l16) * 64 + quad * 8;
#pragma unroll
    for (int kk = 0; kk < 2; kk++) {
      wq[et][kk] = *(const bf16x8*)(wqkv + hcol * 64 + ro + kk * 32);
      wk[et][kk] = *(const bf16x8*)(wqkv + 49152 + hcol * 64 + ro + kk * 32);
      wv[et][kk] = *(const bf16x8*)(wqkv + 98304 + hcol * 64 + ro + kk * 32);
    }
  }

  // ---- staging: wave w does tile-pairs jp = w, w+4 (tiles 2jp, 2jp+1) ----
#pragma unroll
  for (int pi = 0; pi < 2; pi++) {
    const int jp = w + 4 * pi;
    if (jp <= 6) {
      bf16x8 xf[2][2];  // [tile-in-pair][kk]
#pragma unroll
      for (int s2 = 0; s2 < 2; s2++) {
        const int tt = 2 * jp + s2;
        if (tt < 13) {
          int ss = tt * 16 + l16;
          ss = (ss < 197) ? ss : 196;  // clamped rows only feed masked outputs
#pragma unroll
          for (int kk = 0; kk < 2; kk++) {
            const int col = hcol + kk * 32 + quad * 8;
            const fx4* px = (const fx4*)(tok + (size_t)(b * 197 + ss) * 768 + col);
            const fx4* pw = (const fx4*)(lnw + (size_t)ss * 768 + col);
            const fx4* pb = (const fx4*)(lnb + (size_t)ss * 768 + col);
            fx4 y0 = (px[0] - mean) * rstd * pw[0] + pb[0];
            fx4 y1 = (px[1] - mean) * rstd * pw[1] + pb[1];
            xf[s2][kk] = __builtin_bit_cast(bf16x8, pack8(y0, y1));
          }
          fx4 aq[4], ak[4];
#pragma unroll
          for (int et = 0; et < 4; et++) {
            aq[et] = (fx4){0.f, 0.f, 0.f, 0.f};
            ak[et] = (fx4){0.f, 0.f, 0.f, 0.f};
          }
#pragma unroll
          for (int kk = 0; kk < 2; kk++)
#pragma unroll
            for (int et = 0; et < 4; et++) {
              aq[et] = MFMA16(wq[et][kk], xf[s2][kk], aq[et]);  // D[e][s], col=s=l16
              ak[et] = MFMA16(wk[et][kk], xf[s2][kk], ak[et]);
            }
          uint2v qp[4], kp[4];
#pragma unroll
          for (int et = 0; et < 4; et++) {
            fx4 bqv = *(const fx4*)(bq + hcol + et * 16 + quad * 4);
            fx4 bkv = *(const fx4*)(bk + hcol + et * 16 + quad * 4);
            qp[et] = pack2((aq[et] + bqv) * 0.18033688f);  // 0.125 * log2(e)
            kp[et] = pack2(ak[et] + bkv);
          }
          const int qi = pi * 2 + s2;
#pragma unroll
          for (int kk = 0; kk < 2; kk++) {
            qfr[qi][kk] = xfrm(qp[2 * kk], qp[2 * kk + 1], quad, src0, src1);
            bf16x8 kfrag = xfrm(kp[2 * kk], kp[2 * kk + 1], quad, src0, src1);
            Kf[(tt * 2 + kk) * 64 + lane] = __builtin_bit_cast(ushort8, kfrag);
          }
        }
      }
      // V for the pair: D[t][e], col=e=l16 (reuses xf)
      fx4 av[2][4];
#pragma unroll
      for (int s2 = 0; s2 < 2; s2++)
#pragma unroll
        for (int et = 0; et < 4; et++) av[s2][et] = (fx4){0.f, 0.f, 0.f, 0.f};
#pragma unroll
      for (int s2 = 0; s2 < 2; s2++) {
        const int tt = 2 * jp + s2;
        if (tt < 13) {
#pragma unroll
          for (int kk = 0; kk < 2; kk++)
#pragma unroll
            for (int et = 0; et < 4; et++)
              av[s2][et] = MFMA16(xf[s2][kk], wv[et][kk], av[s2][et]);
        }
      }
#pragma unroll
      for (int et = 0; et < 4; et++) {
        const float bvv = bv[hcol + et * 16 + l16];
        fx4 bb4 = (fx4){bvv, bvv, bvv, bvv};
        uint2v v0 = pack2(av[0][et] + bb4);
        uint2v v1 = pack2(av[1][et] + bb4);
        bf16x8 vfrag = xfrm(v0, v1, quad, src0, src1);
        if (jp < 6) Vf[(et * 6 + jp) * 64 + lane] = __builtin_bit_cast(ushort8, vfrag);
        else if (quad < 2) Vt[et * 32 + lane] = __builtin_bit_cast(ushort8, vfrag);
      }
    }
  }
  __syncthreads();

  // ---- attention: 2-deep pipeline over pairs {2w,2w+1} (pr=0), {2w+8,2w+9} (pr=1) ----
#pragma unroll
  for (int pr = 0; pr < 2; pr++) {
    const int mtA = 2 * w + pr * 8;
    const int mtB = mtA + 1;
    if (mtA < 13) {
      const bool bval = (mtB < 13);
      fx4 sA[13], sB[13];
#pragma unroll
      for (int nt = 0; nt < 13; nt++) {
        sA[nt] = (fx4){0.f, 0.f, 0.f, 0.f};
        sB[nt] = (fx4){0.f, 0.f, 0.f, 0.f};
      }
      __builtin_amdgcn_s_setprio(1);
#pragma unroll
      for (int kk = 0; kk < 2; kk++) {
        bf16x8 qa = qfr[pr * 2][kk];
        bf16x8 qb = qfr[pr * 2 + 1][kk];
#pragma unroll
        for (int nt = 0; nt < 13; nt++) {
          bf16x8 kf = __builtin_bit_cast(bf16x8, Kf[(nt * 2 + kk) * 64 + lane]);
          sA[nt] = MFMA16(kf, qa, sA[nt]);  // D[t][m]: col=m=l16, row=t
          sB[nt] = MFMA16(kf, qb, sB[nt]);
        }
      }
      __builtin_amdgcn_s_setprio(0);

      // softmax over t, two independent chains interleaved; Q prescaled so p = 2^s
      float smA = 0.f, smB = 0.f;
      uint2v pkA[13], pkB[13];
#pragma unroll
      for (int nt = 0; nt < 13; nt++) {
        fx4 pA, pB;
#pragma unroll
        for (int r = 0; r < 4; r++) {
          const bool valid = (nt < 12) | (quad * 4 + r < 5);  // t < 197
          pA[r] = valid ? EXP2(sA[nt][r]) : 0.f;
          pB[r] = (valid && bval) ? EXP2(sB[nt][r]) : 0.f;
          smA += pA[r];
          smB += pB[r];
        }
        pkA[nt] = pack2(pA);
        pkB[nt] = pack2(pB);
      }
      smA += __shfl_xor(smA, 16); smA += __shfl_xor(smA, 32);
      smB += __shfl_xor(smB, 16); smB += __shfl_xor(smB, 32);
      const float invA = 1.0f / smA;
      const float invB = bval ? 1.0f / smB : 0.f;

      // issue out-RMW reads now; latency hides under PV
      const int sgA = mtA * 16 + l16;
      const int sgB = mtB * 16 + l16;
      float* opA = out + ((size_t)b * 197 + (sgA < 197 ? sgA : 196)) * 768 + hcol + quad * 4;
      float* opB = out + ((size_t)b * 197 + (sgB < 197 ? sgB : 196)) * 768 + hcol + quad * 4;
      fx4 curA[4], curB[4];
#pragma unroll
      for (int et = 0; et < 4; et++) {
        curA[et] = *(const fx4*)(opA + et * 16);
        curB[et] = *(const fx4*)(opB + et * 16);
      }

      fx4 oA[4], oB[4];
#pragma unroll
      for (int et = 0; et < 4; et++) {
        oA[et] = (fx4){0.f, 0.f, 0.f, 0.f};
        oB[et] = (fx4){0.f, 0.f, 0.f, 0.f};
      }
      __builtin_amdgcn_s_setprio(1);
#pragma unroll
      for (int kk = 0; kk < 7; kk++) {
        uint4v pfA, pfB;
        if (kk < 6) {
          const int nA = 2 * kk, nB = 2 * kk + 1;
#pragma unroll
          for (int d = 0; d < 2; d++) {
            int a0 = __shfl((int)pkA[nA][d], src0, 64);
            int b0 = __shfl((int)pkA[nB][d], src0, 64);
            pfA[d] = (unsigned int)((quad < 2) ? a0 : b0);
            int a1 = __shfl((int)pkA[nA][d], src1, 64);
            int b1 = __shfl((int)pkA[nB][d], src1, 64);
            pfA[2 + d] = (unsigned int)((quad < 2) ? a1 : b1);
            int c0 = __shfl((int)pkB[nA][d], src0, 64);
            int e0 = __shfl((int)pkB[nB][d], src0, 64);
            pfB[d] = (unsigned int)((quad < 2) ? c0 : e0);
            int c1 = __shfl((int)pkB[nA][d], src1, 64);
            int e1 = __shfl((int)pkB[nB][d], src1, 64);
            pfB[2 + d] = (unsigned int)((quad < 2) ? c1 : e1);
          }
        } else {
#pragma unroll
          for (int d = 0; d < 2; d++) {
            int a0 = __shfl((int)pkA[12][d], src0, 64);
            pfA[d] = (quad < 2) ? (unsigned int)a0 : 0u;
            int a1 = __shfl((int)pkA[12][d], src1, 64);
            pfA[2 + d] = (quad < 2) ? (unsigned int)a1 : 0u;
            int c0 = __shfl((int)pkB[12][d], src0, 64);
            pfB[d] = (quad < 2) ? (unsigned int)c0 : 0u;
            int c1 = __shfl((int)pkB[12][d], src1, 64);
            pfB[2 + d] = (quad < 2) ? (unsigned int)c1 : 0u;
          }
        }
        bf16x8 fa = __builtin_bit_cast(bf16x8, pfA);
        bf16x8 fb = __builtin_bit_cast(bf16x8, pfB);
#pragma unroll
        for (int et = 0; et < 4; et++) {
          bf16x8 vf;
          if (kk < 6) {
            vf = __builtin_bit_cast(bf16x8, Vf[(et * 6 + kk) * 64 + lane]);
          } else if (quad < 2) {
            vf = __builtin_bit_cast(bf16x8, Vt[et * 32 + lane]);
          } else {
            ushort8 z = {0, 0, 0, 0, 0, 0, 0, 0};
            vf = __builtin_bit_cast(bf16x8, z);
          }
          oA[et] = MFMA16(vf, fa, oA[et]);  // D[e][m]: col=m=l16, row=e
          oB[et] = MFMA16(vf, fb, oB[et]);
        }
      }
      __builtin_amdgcn_s_setprio(0);

      if (sgA < 197) {
#pragma unroll
        for (int et = 0; et < 4; et++) *(fx4*)(opA + et * 16) = curA[et] + oA[et] * invA;
      }
      if (bval && sgB < 197) {
#pragma unroll
        for (int et = 0; et < 4; et++) *(fx4*)(opB + et * 16) = curB[et] + oB[et] * invB;
      }
    }
  }
}

extern "C" void kernel_launch(void* const* d_in, const int* in_sizes, int n_in,
                              void* d_out, int out_size, void* d_ws, size_t ws_size,
                              hipStream_t stream) {
  (void)in_sizes; (void)n_in; (void)out_size; (void)ws_size;
  const float* img  = (const float*)d_in[0];
  const float* Wmap = (const float*)d_in[1];
  const float* bmap = (const float*)d_in[2];
  const float* ct   = (const float*)d_in[3];
  const float* lnw  = (const float*)d_in[4];
  const float* lnb  = (const float*)d_in[5];
  const float* Wq   = (const float*)d_in[6];
  const float* bq   = (const float*)d_in[7];
  const float* Wk   = (const float*)d_in[8];
  const float* bk   = (const float*)d_in[9];
  const float* Wv   = (const float*)d_in[10];
  const float* bv   = (const float*)d_in[11];
  float* out = (float*)d_out;

  // ws layout (~41 MiB): pe | sums | sqs | W_bf16 | img_bf16 | Wqkv_bf16
  float* pe   = (float*)d_ws;                 // 151296 f
  float* sums = pe + 151296;                  // 128 f
  float* sqs  = sums + 128;                   // 128 f
  unsigned short* wbf   = (unsigned short*)(sqs + 128);  // 589824 u16
  unsigned short* imgbf = wbf + 589824;                  // 19267584 u16
  unsigned short* wqkv  = imgbf + (size_t)19267584;      // 147456 u16

  k_prep<<<10487, 256, 0, stream>>>(img, Wmap, Wq, Wk, Wv, ct,
                                    pe, imgbf, wbf, wqkv, out, sums, sqs);
  k_tokens<<<1176, 256, 0, stream>>>(imgbf, wbf, bmap, pe, out, sums, sqs);
  k_fused<<<1536, 256, 0, stream>>>(out, sums, sqs, lnw, lnb, wqkv, bq, bk, bv, out);
}